// Round 9
// baseline (10785.981 us; speedup 1.0000x reference)
//
#include <hip/hip_runtime.h>
#include <math.h>

#define BB 8      // batch
#define KCH 10    // Chebyshev order
#define GRD(n) ((int)(((n) + 255) / 256))

__device__ __forceinline__ float elu_f(float x){ return x > 0.f ? x : expf(x) - 1.f; }

// ---------------- small utility kernels ----------------

__global__ void zero_i32(int* __restrict__ p, int n){
  int i = blockIdx.x*256 + threadIdx.x;
  if (i < n) p[i] = 0;
}

__global__ void copy_i32(const int* __restrict__ s, int* __restrict__ d, int n){
  int i = blockIdx.x*256 + threadIdx.x;
  if (i < n) d[i] = s[i];
}

// x input is [B, V] fp32 -> x0 [V, B] fp32
__global__ void transpose_in(const float* __restrict__ x, float* __restrict__ x0, int V){
  int i = blockIdx.x*256 + threadIdx.x;
  if (i < BB*V){
    int b = i / V, v = i - b*V;
    x0[(long)v*BB + b] = x[i];
  }
}

// ---------------- CSR build: global atomics (fast; m20-verified HW path) ----------------

__global__ void hist_k(const int* __restrict__ rows, int* __restrict__ cnt, int E){
  int e = blockIdx.x*256 + threadIdx.x;
  if (e < E) atomicAdd(&cnt[rows[e]], 1);
}

// single-block exclusive scan: cnt[0..V-1] -> rp[0..V]  (proven in R6/R7/R8)
__global__ void scan_k(const int* __restrict__ cnt, int* __restrict__ rp, int V){
  __shared__ int sh[1024];
  __shared__ int carry;
  if (threadIdx.x == 0) carry = 0;
  __syncthreads();
  for (int base = 0; base < V; base += 1024){
    int i = base + (int)threadIdx.x;
    int v = (i < V) ? cnt[i] : 0;
    sh[threadIdx.x] = v;
    __syncthreads();
    for (int off = 1; off < 1024; off <<= 1){
      int t = (threadIdx.x >= (unsigned)off) ? sh[threadIdx.x - off] : 0;
      __syncthreads();
      sh[threadIdx.x] += t;
      __syncthreads();
    }
    if (i < V) rp[i] = sh[threadIdx.x] - v + carry;
    __syncthreads();
    if (threadIdx.x == 0) carry += sh[1023];
    __syncthreads();
  }
  if (threadIdx.x == 0) rp[V] = carry;
}

__global__ void scatter_k(const int* __restrict__ rows, const int* __restrict__ cols,
                          const float* __restrict__ vals, int* __restrict__ cur,
                          int* __restrict__ cs, float* __restrict__ vs, int E){
  int e = blockIdx.x*256 + threadIdx.x;
  if (e < E){
    int r = rows[e];
    int p = atomicAdd(&cur[r], 1);
    cs[p] = cols[e];
    vs[p] = vals[e];
  }
}

// ---------------- device-scope grid barrier ----------------
// bar[0]=cnt, bar[1]=gen, bar[2]=poison (timeout bail so a failure can't hang)
__device__ void grid_barrier(int* bar, int nb){
  __syncthreads();
  if (threadIdx.x == 0){
    if (__hip_atomic_load(&bar[2], __ATOMIC_RELAXED, __HIP_MEMORY_SCOPE_AGENT) == 0){
      __threadfence();
      int g = __hip_atomic_load(&bar[1], __ATOMIC_RELAXED, __HIP_MEMORY_SCOPE_AGENT);
      int a = __hip_atomic_fetch_add(&bar[0], 1, __ATOMIC_ACQ_REL, __HIP_MEMORY_SCOPE_AGENT);
      if (a == nb - 1){
        __hip_atomic_store(&bar[0], 0, __ATOMIC_RELAXED, __HIP_MEMORY_SCOPE_AGENT);
        __threadfence();
        __hip_atomic_fetch_add(&bar[1], 1, __ATOMIC_ACQ_REL, __HIP_MEMORY_SCOPE_AGENT);
      } else {
        long long t0 = (long long)clock64();
        while (__hip_atomic_load(&bar[1], __ATOMIC_RELAXED, __HIP_MEMORY_SCOPE_AGENT) == g){
          __builtin_amdgcn_s_sleep(2);
          if ((long long)clock64() - t0 > 150000000LL){   // bail: never hang the bench
            __hip_atomic_store(&bar[2], 1, __ATOMIC_RELAXED, __HIP_MEMORY_SCOPE_AGENT);
            break;
          }
        }
      }
      __threadfence();
    }
  }
  __syncthreads();
}

// ---------------- persistent fused ChebConv ----------------
// One block per CU (LDS-padded to force 1/CU). Block owns VPB vertices.
// Per k: gather x_k rows (write once to global, skip at k=K-1), stage tile in
// LDS, accumulate C += x_k @ W_k in registers. C written once at the end.
template<int VPB, int Ci, int Co, int TILE_V, int DO_ELU>
__global__ __launch_bounds__(1024, 4) void cheb_coop(
    const float* __restrict__ W, const float* __restrict__ bias,
    float* x0in, float* p1, float* p2,
    const int* __restrict__ rp, const int* __restrict__ cs,
    const float* __restrict__ vs,
    float* __restrict__ C, int* bar)
{
  constexpr int STRIPES = 1024 / (8*Co);
  constexpr int VT    = TILE_V / STRIPES;     // vertices per thread per tile
  constexpr int TILES = VPB / TILE_V;
  constexpr int NACC  = TILES * VT;
  constexpr int F4    = 2*Ci;                 // float4 per vertex row (F = 8*Ci)
  constexpr int ITEMS = TILE_V * Ci;          // float4-pairs per tile
  constexpr int XL    = TILE_V * 8 * Ci;
  __shared__ float Wlds[Ci*Co];
  __shared__ float xlds[XL];
  constexpr int USED = (Ci*Co + XL)*4;
  constexpr int PADB = (USED < 84*1024) ? (84*1024 - USED) : 4;
  __shared__ char padlds[PADB];               // force <=1 block/CU (co-residency)
  if (blockIdx.x == 0xFFFFFFFFu) ((volatile char*)padlds)[0] = 1;  // keep alive

  const int tid = (int)threadIdx.x;
  const int gr0 = (int)blockIdx.x * VPB;
  const int co = tid % Co;
  const int b  = (tid / Co) & 7;
  const int stripe = tid / (8*Co);

  float acc[NACC];
  #pragma unroll
  for (int i = 0; i < NACC; i++) acc[i] = 0.f;

  float *ra = x0in, *rb = p1, *rc = p2;       // x_{k-2}, x_{k-1}, free

  for (int k = 0; k < KCH; k++){
    const float* Wk = W + (size_t)k*Ci*Co;
    for (int i = tid; i < Ci*Co; i += 1024) Wlds[i] = Wk[i];
    __syncthreads();

    const float4* src4 = (const float4*)((k <= 1) ? x0in : rb);
    const float4* prv4 = (const float4*)ra;
    float4* dst4 = (float4*)((k == 1) ? p1 : rc);
    const float alpha = (k == 1) ? 1.f : 2.f;

    #pragma unroll
    for (int tile = 0; tile < TILES; tile++){
      const int vbase = gr0 + tile*TILE_V;
      if (k == 0){
        for (int it = tid; it < ITEMS; it += 1024){
          int vl = it / Ci, f8 = it - vl*Ci;
          const float4* sp = src4 + ((long)(vbase+vl)*F4 + 2*f8);
          float4 a0 = sp[0], a1 = sp[1];
          ((float4*)xlds)[vl*F4 + 2*f8]     = a0;
          ((float4*)xlds)[vl*F4 + 2*f8 + 1] = a1;
        }
      } else {
        for (int it = tid; it < ITEMS; it += 1024){
          int vl = it / Ci, f8 = it - vl*Ci;
          int gv = vbase + vl;
          int j0 = rp[gv], j1 = rp[gv+1];
          float4 A = {0,0,0,0}, Bv = {0,0,0,0};
          for (int j = j0; j < j1; j++){
            int cc = cs[j]; float vv = vs[j];
            const float4* g = src4 + ((long)cc*F4 + 2*f8);
            float4 g0 = g[0], g1 = g[1];
            A.x  = fmaf(vv, g0.x, A.x);  A.y  = fmaf(vv, g0.y, A.y);
            A.z  = fmaf(vv, g0.z, A.z);  A.w  = fmaf(vv, g0.w, A.w);
            Bv.x = fmaf(vv, g1.x, Bv.x); Bv.y = fmaf(vv, g1.y, Bv.y);
            Bv.z = fmaf(vv, g1.z, Bv.z); Bv.w = fmaf(vv, g1.w, Bv.w);
          }
          float4 r0, r1;
          r0.x = alpha*A.x;  r0.y = alpha*A.y;  r0.z = alpha*A.z;  r0.w = alpha*A.w;
          r1.x = alpha*Bv.x; r1.y = alpha*Bv.y; r1.z = alpha*Bv.z; r1.w = alpha*Bv.w;
          if (k >= 2){   // beta = -1
            const float4* pp = prv4 + ((long)gv*F4 + 2*f8);
            float4 p0 = pp[0], p1v = pp[1];
            r0.x -= p0.x;  r0.y -= p0.y;  r0.z -= p0.z;  r0.w -= p0.w;
            r1.x -= p1v.x; r1.y -= p1v.y; r1.z -= p1v.z; r1.w -= p1v.w;
          }
          ((float4*)xlds)[vl*F4 + 2*f8]     = r0;
          ((float4*)xlds)[vl*F4 + 2*f8 + 1] = r1;
          if (k < KCH-1){   // x_{K-1} only feeds the last GEMM
            dst4[(long)gv*F4 + 2*f8]     = r0;
            dst4[(long)gv*F4 + 2*f8 + 1] = r1;
          }
        }
      }
      __syncthreads();

      // GEMM accumulate: acc += x_tile @ Wk
      if (Ci == 1){
        float wv = Wlds[co];
        #pragma unroll
        for (int j = 0; j < VT; j++){
          int vt = stripe + j*STRIPES;
          acc[tile*VT + j] = fmaf(xlds[vt*8 + b], wv, acc[tile*VT + j]);
        }
      } else {
        for (int ci0 = 0; ci0 < Ci; ci0 += 8){
          float wr[8];
          #pragma unroll
          for (int w = 0; w < 8; w++) wr[w] = Wlds[(ci0+w)*Co + co];
          #pragma unroll
          for (int j = 0; j < VT; j++){
            int vt = stripe + j*STRIPES;
            const float4* xp = (const float4*)&xlds[(vt*8 + b)*Ci + ci0];
            float4 xa = xp[0], xb2 = xp[1];
            float s = acc[tile*VT + j];
            s = fmaf(xa.x,  wr[0], s); s = fmaf(xa.y,  wr[1], s);
            s = fmaf(xa.z,  wr[2], s); s = fmaf(xa.w,  wr[3], s);
            s = fmaf(xb2.x, wr[4], s); s = fmaf(xb2.y, wr[5], s);
            s = fmaf(xb2.z, wr[6], s); s = fmaf(xb2.w, wr[7], s);
            acc[tile*VT + j] = s;
          }
        }
      }
      __syncthreads();
    }

    if (k >= 2){ float* t = ra; ra = rb; rb = rc; rc = t; }
    if (k >= 1 && k < KCH-1) grid_barrier(bar, (int)gridDim.x);
  }

  // writeback C (once). conv1 fuses bias+ELU.
  float bia = DO_ELU ? bias[co] : 0.f;
  #pragma unroll
  for (int tile = 0; tile < TILES; tile++){
    #pragma unroll
    for (int j = 0; j < VT; j++){
      int gv = gr0 + tile*TILE_V + stripe + j*STRIPES;
      float v = acc[tile*VT + j];
      if (DO_ELU) v = elu_f(v + bia);
      C[((long)gv*8 + b)*Co + co] = v;
    }
  }
}

// out2 [V,B,C] pre-bias -> skip (d_out [B,V,C]), pooled -> nx [V/4,B,C],
// optional pooled -> pool_out (d_out [B,V/4,C])
__global__ void epilogue_k(const float* __restrict__ out2, const float* __restrict__ bias,
                           float* __restrict__ skip_out, float* __restrict__ nx,
                           float* __restrict__ pool_out, int V, int C){
  long t = (long)blockIdx.x*256 + threadIdx.x;
  long total = (long)(V/4)*BB*C;
  if (t >= total) return;
  int  c  = (int)(t % C);
  long bv = t / C;
  int  b  = (int)(bv % BB);
  int  v2 = (int)(bv / BB);
  float bia = bias[c];
  float s = 0.f;
  for (int j = 0; j < 4; j++){
    long v = (long)4*v2 + j;
    float val = elu_f(out2[(v*BB + b)*C + c] + bia);
    skip_out[((long)b*V + v)*C + c] = val;
    s += val;
  }
  s *= 0.25f;
  nx[((long)v2*BB + b)*C + c] = s;
  if (pool_out) pool_out[((long)b*(V/4) + v2)*C + c] = s;
}

__global__ void guard_k(float* __restrict__ out0, int code){
  if (threadIdx.x == 0) out0[0] = 1.0e6f + (float)code;
}

// ---------------- host driver ----------------

extern "C" void kernel_launch(void* const* d_in, const int* in_sizes, int n_in,
                              void* d_out, int out_size, void* d_ws, size_t ws_size,
                              hipStream_t stream){
  const float* x_in  = (const float*)d_in[0];
  const float* w1[3] = {(const float*)d_in[1], (const float*)d_in[8],  (const float*)d_in[15]};
  const float* b1[3] = {(const float*)d_in[2], (const float*)d_in[9],  (const float*)d_in[16]};
  const float* w2[3] = {(const float*)d_in[3], (const float*)d_in[10], (const float*)d_in[17]};
  const float* b2[3] = {(const float*)d_in[4], (const float*)d_in[11], (const float*)d_in[18]};
  const int*  rows[3]= {(const int*)d_in[5],   (const int*)d_in[12],   (const int*)d_in[19]};
  const int*  cols[3]= {(const int*)d_in[6],   (const int*)d_in[13],   (const int*)d_in[20]};
  const float* vals[3]={(const float*)d_in[7], (const float*)d_in[14], (const float*)d_in[21]};
  float* out = (float*)d_out;

  const int V[3] = {49152, 12288, 3072};
  const int E[3] = {393216, 98304, 24576};

  // ---- workspace layout (fp32 units) ----
  float* wsf = (float*)d_ws;
  size_t off = 0;
  const size_t BUFSZ = (size_t)49152 * BB * 32;   // 12,582,912 floats
  float* BUF0 = wsf + off; off += BUFSZ;
  float* BUF1 = wsf + off; off += BUFSZ;
  float* BUF2 = wsf + off; off += BUFSZ;
  float* BUF3 = wsf + off; off += BUFSZ;
  float* NX   = wsf + off; off += (size_t)12288 * BB * 32;
  int* rp[3]; int* cs[3]; float* vsf[3];
  for (int i = 0; i < 3; i++){
    rp[i]  = (int*)(wsf + off); off += V[i] + 1;
    cs[i]  = (int*)(wsf + off); off += E[i];
    vsf[i] =        wsf + off;  off += E[i];
  }
  int* cnt = (int*)(wsf + off); off += 49152;
  int* cur = (int*)(wsf + off); off += 49152;
  int* bar = (int*)(wsf + off); off += 16;
  if (ws_size < off * sizeof(float)) return;

  // ---- barrier init (ws is re-poisoned every call) ----
  zero_i32<<<1, 256, 0, stream>>>(bar, 16);

  // ---- CSR build per level: global atomics ----
  for (int i = 0; i < 3; i++){
    zero_i32 <<<GRD(V[i]), 256, 0, stream>>>(cnt, V[i]);
    hist_k   <<<GRD(E[i]), 256, 0, stream>>>(rows[i], cnt, E[i]);
    scan_k   <<<1, 1024, 0, stream>>>(cnt, rp[i], V[i]);
    copy_i32 <<<GRD(V[i]), 256, 0, stream>>>(rp[i], cur, V[i]);
    scatter_k<<<GRD(E[i]), 256, 0, stream>>>(rows[i], cols[i], vals[i],
                                             cur, cs[i], vsf[i], E[i]);
  }

  // ---- level 0 input: [B,V] -> [V,B,1] ----
  transpose_in<<<GRD(BB*V[0]), 256, 0, stream>>>(x_in, NX, V[0]);

  const long OFF_OUT[4] = {0, 12582912, 18874368, 22020096};
  dim3 cgrid(256), cblk(1024);

  // ---- level 0 ----
  cheb_coop<192,1,32,192,1><<<cgrid, cblk, 0, stream>>>(
      w1[0], b1[0], NX, BUF1, BUF2, rp[0], cs[0], vsf[0], BUF0, bar);
  cheb_coop<192,32,32,96,0><<<cgrid, cblk, 0, stream>>>(
      w2[0], nullptr, BUF0, BUF1, BUF2, rp[0], cs[0], vsf[0], BUF3, bar);
  epilogue_k<<<GRD((long)(V[0]/4)*BB*32), 256, 0, stream>>>(
      BUF3, b2[0], out + OFF_OUT[0], NX, nullptr, V[0], 32);

  // ---- level 1 ----
  cheb_coop<48,32,64,48,1><<<cgrid, cblk, 0, stream>>>(
      w1[1], b1[1], NX, BUF1, BUF2, rp[1], cs[1], vsf[1], BUF0, bar);
  cheb_coop<48,64,64,24,0><<<cgrid, cblk, 0, stream>>>(
      w2[1], nullptr, BUF0, BUF1, BUF2, rp[1], cs[1], vsf[1], BUF3, bar);
  epilogue_k<<<GRD((long)(V[1]/4)*BB*64), 256, 0, stream>>>(
      BUF3, b2[1], out + OFF_OUT[1], NX, nullptr, V[1], 64);

  // ---- level 2 ----
  cheb_coop<12,64,128,12,1><<<cgrid, cblk, 0, stream>>>(
      w1[2], b1[2], NX, BUF1, BUF2, rp[2], cs[2], vsf[2], BUF0, bar);
  cheb_coop<12,128,128,12,0><<<cgrid, cblk, 0, stream>>>(
      w2[2], nullptr, BUF0, BUF1, BUF2, rp[2], cs[2], vsf[2], BUF3, bar);
  epilogue_k<<<GRD((long)(V[2]/4)*BB*128), 256, 0, stream>>>(
      BUF3, b2[2], out + OFF_OUT[2], NX, out + OFF_OUT[3], V[2], 128);

  if (out_size != 22806528)
    guard_k<<<1, 64, 0, stream>>>(out, out_size % 4096);
}

// Round 10
// 3695.381 us; speedup vs baseline: 2.9188x; 2.9188x over previous
//
#include <hip/hip_runtime.h>
#include <math.h>

#define BB 8      // batch
#define KCH 10    // Chebyshev order
#define ROWS 64   // GEMM rows per block
#define GRD(n) ((int)(((n) + 255) / 256))

__device__ __forceinline__ float elu_f(float x){ return x > 0.f ? x : expf(x) - 1.f; }

// ---------------- utility ----------------

__global__ void zero_i32(int* __restrict__ p, int n){
  int i = blockIdx.x*256 + threadIdx.x;
  if (i < n) p[i] = 0;
}

__global__ void copy_i32(const int* __restrict__ s, int* __restrict__ d, int n){
  int i = blockIdx.x*256 + threadIdx.x;
  if (i < n) d[i] = s[i];
}

// x input is [B, V] fp32 -> x0 [V, B] fp32
__global__ void transpose_in(const float* __restrict__ x, float* __restrict__ x0, int V){
  int i = blockIdx.x*256 + threadIdx.x;
  if (i < BB*V){
    int b = i / V, v = i - b*V;
    x0[(long)v*BB + b] = x[i];
  }
}

// ---------------- CSR build: global atomics (correctness-proven in R9) ----------------

__global__ void hist_k(const int* __restrict__ rows, int* __restrict__ cnt, int E){
  int e = blockIdx.x*256 + threadIdx.x;
  if (e < E) atomicAdd(&cnt[rows[e]], 1);
}

__global__ void scan_k(const int* __restrict__ cnt, int* __restrict__ rp, int V){
  __shared__ int sh[1024];
  __shared__ int carry;
  if (threadIdx.x == 0) carry = 0;
  __syncthreads();
  for (int base = 0; base < V; base += 1024){
    int i = base + (int)threadIdx.x;
    int v = (i < V) ? cnt[i] : 0;
    sh[threadIdx.x] = v;
    __syncthreads();
    for (int off = 1; off < 1024; off <<= 1){
      int t = (threadIdx.x >= (unsigned)off) ? sh[threadIdx.x - off] : 0;
      __syncthreads();
      sh[threadIdx.x] += t;
      __syncthreads();
    }
    if (i < V) rp[i] = sh[threadIdx.x] - v + carry;
    __syncthreads();
    if (threadIdx.x == 0) carry += sh[1023];
    __syncthreads();
  }
  if (threadIdx.x == 0) rp[V] = carry;
}

__global__ void scatter_k(const int* __restrict__ rows, const int* __restrict__ cols,
                          const float* __restrict__ vals, int* __restrict__ cur,
                          int* __restrict__ cs, float* __restrict__ vs, int E){
  int e = blockIdx.x*256 + threadIdx.x;
  if (e < E){
    int r = rows[e];
    int p = atomicAdd(&cur[r], 1);
    cs[p] = cols[e];
    vs[p] = vals[e];
  }
}

// ---------------- SpMV gathers ----------------

// Narrow path (F4 < 64; only Ci=1): per-thread edge loop.
__global__ __launch_bounds__(256) void spmv_narrow(
    const int* __restrict__ rp, const int* __restrict__ cs, const float* __restrict__ vs,
    const float4* __restrict__ xin, const float4* __restrict__ xprev,
    float4* __restrict__ xout, int V, int lf4, float alpha, float beta){
  long t = (long)blockIdx.x*256 + threadIdx.x;
  if (t >= ((long)V << lf4)) return;
  int r  = (int)(t >> lf4);
  int f4 = (int)(t & ((1 << lf4) - 1));
  int j0 = rp[r], j1 = rp[r+1];
  float ax = 0.f, ay = 0.f, az = 0.f, aw = 0.f;
  for (int j = j0; j < j1; j++){
    int   c = cs[j];
    float v = vs[j];
    float4 g = xin[((long)c << lf4) + f4];
    ax = fmaf(v, g.x, ax); ay = fmaf(v, g.y, ay);
    az = fmaf(v, g.z, az); aw = fmaf(v, g.w, aw);
  }
  float4 o;
  o.x = alpha*ax; o.y = alpha*ay; o.z = alpha*az; o.w = alpha*aw;
  if (xprev){
    float4 p = xprev[t];
    o.x = fmaf(beta, p.x, o.x); o.y = fmaf(beta, p.y, o.y);
    o.z = fmaf(beta, p.z, o.z); o.w = fmaf(beta, p.w, o.w);
  }
  xout[t] = o;
}

// Wide path (F4 >= 64): a wave's 64 lanes share one row r. Lane j preloads
// cs/vs[j0+j]; __shfl broadcasts -> all gather loads issue back-to-back (MLP).
__global__ __launch_bounds__(256) void spmv_wide(
    const int* __restrict__ rp, const int* __restrict__ cs, const float* __restrict__ vs,
    const float4* __restrict__ xin, const float4* __restrict__ xprev,
    float4* __restrict__ xout, int V, int lf4, float alpha, float beta){
  long t = (long)blockIdx.x*256 + threadIdx.x;
  if (t >= ((long)V << lf4)) return;
  int r    = (int)(t >> lf4);
  int f4   = (int)(t & ((1 << lf4) - 1));
  int lane = (int)(threadIdx.x & 63);
  int j0 = rp[r], j1 = rp[r+1];          // wave-uniform (F4 >= 64)
  float ax = 0.f, ay = 0.f, az = 0.f, aw = 0.f;
  for (int base = j0; base < j1; base += 64){
    int jj = base + lane;
    int   myc = (jj < j1) ? cs[jj] : 0;
    float myv = (jj < j1) ? vs[jj] : 0.f;
    int nn = j1 - base; if (nn > 64) nn = 64;
    for (int m = 0; m < nn; m++){
      int   c = __shfl(myc, m);
      float v = __shfl(myv, m);
      float4 g = xin[((long)c << lf4) + f4];
      ax = fmaf(v, g.x, ax); ay = fmaf(v, g.y, ay);
      az = fmaf(v, g.z, az); aw = fmaf(v, g.w, aw);
    }
  }
  float4 o;
  o.x = alpha*ax; o.y = alpha*ay; o.z = alpha*az; o.w = alpha*aw;
  if (xprev){
    float4 p = xprev[t];
    o.x = fmaf(beta, p.x, o.x); o.y = fmaf(beta, p.y, o.y);
    o.z = fmaf(beta, p.z, o.z); o.w = fmaf(beta, p.w, o.w);
  }
  xout[t] = o;
}

// ---------------- pair-k GEMM: C (acc?+=:=) A0@Wk + A1@Wk+1 ----------------
// Static LDS (R9 proved >64KB static works). Thread (tc=tid&15, tr=tid>>4)
// computes 4 rows x TN cols. Optional fused bias+ELU on the final pass.
template<int Ci, int Co>
__global__ __launch_bounds__(256) void gemm2_k(
    const float* __restrict__ A0, const float* __restrict__ A1,
    const float* __restrict__ W,    // points at w + k*Ci*Co; reads 2 consecutive
    const float* __restrict__ bias, float* __restrict__ C,
    int acc, int do_elu){
  constexpr int TN = Co / 16;
  __shared__ float ws[2*Ci*Co];
  int tid = (int)threadIdx.x;
  for (int i = tid; i < 2*Ci*Co; i += 256) ws[i] = W[i];
  __syncthreads();

  const int tc = tid & 15, tr = tid >> 4;
  const long r0 = (long)blockIdx.x * ROWS + (long)tr * 4;

  float accv[4][TN];
  #pragma unroll
  for (int m = 0; m < 4; m++)
    #pragma unroll
    for (int j = 0; j < TN; j++) accv[m][j] = 0.f;

  #pragma unroll
  for (int kk = 0; kk < 2; kk++){
    const float* Ar = (kk == 0 ? A0 : A1) + r0 * Ci;
    const float* wk = &ws[kk*Ci*Co];
    if (Ci >= 4){
      for (int i = 0; i < Ci; i += 4){
        float4 a0 = *(const float4*)(Ar + 0*Ci + i);
        float4 a1 = *(const float4*)(Ar + 1*Ci + i);
        float4 a2 = *(const float4*)(Ar + 2*Ci + i);
        float4 a3 = *(const float4*)(Ar + 3*Ci + i);
        float am[4][4] = {{a0.x,a0.y,a0.z,a0.w},{a1.x,a1.y,a1.z,a1.w},
                          {a2.x,a2.y,a2.z,a2.w},{a3.x,a3.y,a3.z,a3.w}};
        #pragma unroll
        for (int ii = 0; ii < 4; ii++){
          const float* wr = &wk[(i+ii)*Co + tc];
          #pragma unroll
          for (int j = 0; j < TN; j++){
            float wv = wr[j*16];
            #pragma unroll
            for (int m = 0; m < 4; m++)
              accv[m][j] = fmaf(am[m][ii], wv, accv[m][j]);
          }
        }
      }
    } else {  // Ci == 1
      float am[4] = {Ar[0], Ar[1], Ar[2], Ar[3]};
      const float* wr = &wk[tc];
      #pragma unroll
      for (int j = 0; j < TN; j++){
        float wv = wr[j*16];
        #pragma unroll
        for (int m = 0; m < 4; m++)
          accv[m][j] = fmaf(am[m], wv, accv[m][j]);
      }
    }
  }

  #pragma unroll
  for (int m = 0; m < 4; m++){
    float* Cr = C + (r0 + m)*Co;
    #pragma unroll
    for (int j = 0; j < TN; j++){
      int col = tc + j*16;
      float v = accv[m][j];
      if (acc) v += Cr[col];
      if (do_elu) v = elu_f(v + bias[col]);
      Cr[col] = v;
    }
  }
}

// out2 [V,B,C] pre-bias -> skip (d_out [B,V,C]), pooled -> nx [V/4,B,C],
// optional pooled -> pool_out (d_out [B,V/4,C])
__global__ void epilogue_k(const float* __restrict__ out2, const float* __restrict__ bias,
                           float* __restrict__ skip_out, float* __restrict__ nx,
                           float* __restrict__ pool_out, int V, int C){
  long t = (long)blockIdx.x*256 + threadIdx.x;
  long total = (long)(V/4)*BB*C;
  if (t >= total) return;
  int  c  = (int)(t % C);
  long bv = t / C;
  int  b  = (int)(bv % BB);
  int  v2 = (int)(bv / BB);
  float bia = bias[c];
  float s = 0.f;
  for (int j = 0; j < 4; j++){
    long v = (long)4*v2 + j;
    float val = elu_f(out2[(v*BB + b)*C + c] + bia);
    skip_out[((long)b*V + v)*C + c] = val;
    s += val;
  }
  s *= 0.25f;
  nx[((long)v2*BB + b)*C + c] = s;
  if (pool_out) pool_out[((long)b*(V/4) + v2)*C + c] = s;
}

__global__ void guard_k(float* __restrict__ out0, int code){
  if (threadIdx.x == 0) out0[0] = 1.0e6f + (float)code;
}

// ---------------- host driver ----------------

static int ilog2(int x){ int l = 0; while ((1 << l) < x) l++; return l; }

static void launch_spmv(const int* rp, const int* cs, const float* vs,
                        const float* xin, const float* xprev, float* xout,
                        int V, int Ci, float alpha, float beta, hipStream_t stream){
  int F4 = BB*Ci/4;
  int lf4 = ilog2(F4);
  long n4 = (long)V*F4;
  if (F4 >= 64)
    spmv_wide<<<GRD(n4), 256, 0, stream>>>(rp, cs, vs, (const float4*)xin,
                                           (const float4*)xprev, (float4*)xout,
                                           V, lf4, alpha, beta);
  else
    spmv_narrow<<<GRD(n4), 256, 0, stream>>>(rp, cs, vs, (const float4*)xin,
                                             (const float4*)xprev, (float4*)xout,
                                             V, lf4, alpha, beta);
}

template<int Ci, int Co>
static void run_cheb_t(float* IN, float* P1, float* P2, float* Cout,
                       const float* w, const float* bias,
                       int V, const int* rp, const int* cs, const float* vs,
                       hipStream_t stream){
  long M = (long)V*BB;
  int grid = (int)(M / ROWS);
  float* S[3] = {IN, P1, P2};

  // k = 1: x1 = L x0
  launch_spmv(rp, cs, vs, S[0], nullptr, S[1], V, Ci, 1.f, 0.f, stream);
  // GEMM k=0,1
  gemm2_k<Ci,Co><<<grid, 256, 0, stream>>>(S[0], S[1], w, bias, Cout, 0, 0);

  for (int m = 1; m <= 4; m++){
    int k = 2*m;
    // x_k = 2 L x_{k-1} - x_{k-2}
    launch_spmv(rp, cs, vs, S[(k-1)%3], S[(k-2)%3], S[k%3], V, Ci, 2.f, -1.f, stream);
    // x_{k+1} = 2 L x_k - x_{k-1}
    launch_spmv(rp, cs, vs, S[k%3], S[(k-1)%3], S[(k+1)%3], V, Ci, 2.f, -1.f, stream);
    int elu = (bias && m == 4) ? 1 : 0;
    gemm2_k<Ci,Co><<<grid, 256, 0, stream>>>(S[k%3], S[(k+1)%3],
                                             w + (size_t)k*Ci*Co, bias, Cout, 1, elu);
  }
}

extern "C" void kernel_launch(void* const* d_in, const int* in_sizes, int n_in,
                              void* d_out, int out_size, void* d_ws, size_t ws_size,
                              hipStream_t stream){
  const float* x_in  = (const float*)d_in[0];
  const float* w1[3] = {(const float*)d_in[1], (const float*)d_in[8],  (const float*)d_in[15]};
  const float* b1[3] = {(const float*)d_in[2], (const float*)d_in[9],  (const float*)d_in[16]};
  const float* w2[3] = {(const float*)d_in[3], (const float*)d_in[10], (const float*)d_in[17]};
  const float* b2[3] = {(const float*)d_in[4], (const float*)d_in[11], (const float*)d_in[18]};
  const int*  rows[3]= {(const int*)d_in[5],   (const int*)d_in[12],   (const int*)d_in[19]};
  const int*  cols[3]= {(const int*)d_in[6],   (const int*)d_in[13],   (const int*)d_in[20]};
  const float* vals[3]={(const float*)d_in[7], (const float*)d_in[14], (const float*)d_in[21]};
  float* out = (float*)d_out;

  const int V[3] = {49152, 12288, 3072};
  const int E[3] = {393216, 98304, 24576};

  // ---- workspace layout (fp32 units) — within the R8/R9-proven footprint ----
  float* wsf = (float*)d_ws;
  size_t off = 0;
  const size_t BUFSZ = (size_t)49152 * BB * 32;   // 12,582,912 floats
  float* BUF0 = wsf + off; off += BUFSZ;          // conv1 out / conv2 IN slot
  float* BUF1 = wsf + off; off += BUFSZ;          // P1
  float* BUF2 = wsf + off; off += BUFSZ;          // P2
  float* BUF3 = wsf + off; off += BUFSZ;          // conv2 out
  float* NX   = wsf + off; off += (size_t)12288 * BB * 32;  // level input
  int* rp[3]; int* cs[3]; float* vsf[3];
  for (int i = 0; i < 3; i++){
    rp[i]  = (int*)(wsf + off); off += V[i] + 1;
    cs[i]  = (int*)(wsf + off); off += E[i];
    vsf[i] =        wsf + off;  off += E[i];
  }
  int* cnt = (int*)(wsf + off); off += 49152;
  int* cur = (int*)(wsf + off); off += 49152;
  if (ws_size < off * sizeof(float)) return;

  // ---- CSR build per level: global atomics ----
  for (int i = 0; i < 3; i++){
    zero_i32 <<<GRD(V[i]), 256, 0, stream>>>(cnt, V[i]);
    hist_k   <<<GRD(E[i]), 256, 0, stream>>>(rows[i], cnt, E[i]);
    scan_k   <<<1, 1024, 0, stream>>>(cnt, rp[i], V[i]);
    copy_i32 <<<GRD(V[i]), 256, 0, stream>>>(rp[i], cur, V[i]);
    scatter_k<<<GRD(E[i]), 256, 0, stream>>>(rows[i], cols[i], vals[i],
                                             cur, cs[i], vsf[i], E[i]);
  }

  // ---- level 0 input: [B,V] -> [V,B,1] ----
  transpose_in<<<GRD(BB*V[0]), 256, 0, stream>>>(x_in, NX, V[0]);

  const long OFF_OUT[4] = {0, 12582912, 18874368, 22020096};

  // ---- level 0 ----
  run_cheb_t<1,32>  (NX,   BUF1, BUF2, BUF0, w1[0], b1[0], V[0], rp[0], cs[0], vsf[0], stream);
  run_cheb_t<32,32> (BUF0, BUF1, BUF2, BUF3, w2[0], nullptr, V[0], rp[0], cs[0], vsf[0], stream);
  epilogue_k<<<GRD((long)(V[0]/4)*BB*32), 256, 0, stream>>>(
      BUF3, b2[0], out + OFF_OUT[0], NX, nullptr, V[0], 32);

  // ---- level 1 ----
  run_cheb_t<32,64> (NX,   BUF1, BUF2, BUF0, w1[1], b1[1], V[1], rp[1], cs[1], vsf[1], stream);
  run_cheb_t<64,64> (BUF0, BUF1, BUF2, BUF3, w2[1], nullptr, V[1], rp[1], cs[1], vsf[1], stream);
  epilogue_k<<<GRD((long)(V[1]/4)*BB*64), 256, 0, stream>>>(
      BUF3, b2[1], out + OFF_OUT[1], NX, nullptr, V[1], 64);

  // ---- level 2 ----
  run_cheb_t<64,128> (NX,   BUF1, BUF2, BUF0, w1[2], b1[2], V[2], rp[2], cs[2], vsf[2], stream);
  run_cheb_t<128,128>(BUF0, BUF1, BUF2, BUF3, w2[2], nullptr, V[2], rp[2], cs[2], vsf[2], stream);
  epilogue_k<<<GRD((long)(V[2]/4)*BB*128), 256, 0, stream>>>(
      BUF3, b2[2], out + OFF_OUT[2], NX, out + OFF_OUT[3], V[2], 128);

  if (out_size != 22806528)
    guard_k<<<1, 64, 0, stream>>>(out, out_size % 4096);
}